// Round 1
// baseline (605.581 us; speedup 1.0000x reference)
//
#include <hip/hip_runtime.h>
#include <hip/hip_bf16.h>
#include <math.h>

#define SK_EPS 1e-12f

typedef __attribute__((ext_vector_type(8))) short short8;
typedef __attribute__((ext_vector_type(4))) float f32x4;

__device__ __forceinline__ unsigned short f2bf(float f) {
  union { float f; unsigned int u; } c; c.f = f;
  unsigned int u = c.u + 0x7FFFu + ((c.u >> 16) & 1u);
  return (unsigned short)(u >> 16);
}

// ---------------- Kernel 1: global average pool over HW (4096) ----------------
__global__ __launch_bounds__(256) void pool_k(const float* __restrict__ x,
                                              float* __restrict__ pooled) {
  const int row = blockIdx.x;  // b*256 + c
  const float4* xr = reinterpret_cast<const float4*>(x + (size_t)row * 4096);
  const int t = threadIdx.x;
  float s = 0.0f;
#pragma unroll
  for (int k = 0; k < 4; ++k) {
    float4 v = xr[t + k * 256];
    s += v.x + v.y + v.z + v.w;
  }
#pragma unroll
  for (int m = 1; m < 64; m <<= 1) s += __shfl_xor(s, m);
  __shared__ float wsum[4];
  if ((t & 63) == 0) wsum[t >> 6] = s;
  __syncthreads();
  if (t == 0) pooled[row] = (wsum[0] + wsum[1] + wsum[2] + wsum[3]) * (1.0f / 4096.0f);
}

// ---------------- Kernel 2: h = silu(pooled @ w1^T + b1)  [32,64] ----------------
__global__ __launch_bounds__(64) void h_k(const float* __restrict__ pooled,
                                          const float* __restrict__ w1,
                                          const float* __restrict__ b1,
                                          float* __restrict__ h) {
  const int b = blockIdx.x;
  const int r = threadIdx.x;  // 64 threads
  const float4* p4 = reinterpret_cast<const float4*>(pooled + b * 256);
  const float4* w4 = reinterpret_cast<const float4*>(w1 + r * 256);
  float acc = b1[r];
#pragma unroll 8
  for (int k = 0; k < 64; ++k) {
    float4 a = p4[k], w = w4[k];
    acc += a.x * w.x + a.y * w.y + a.z * w.z + a.w * w.w;
  }
  float sig = 1.0f / (1.0f + __expf(-acc));
  h[b * 64 + r] = acc * sig;
}

// ---------------- Kernel 3: weights[b,n] = h[b,:] . w2[n,:] + b2[n] ----------------
__global__ __launch_bounds__(256) void wgen_k(const float* __restrict__ h,
                                              const float* __restrict__ w2,
                                              const float* __restrict__ b2,
                                              float* __restrict__ wout) {
  __shared__ float hs[32][64];
  const int t = threadIdx.x;
  for (int i = t; i < 2048; i += 256) hs[i >> 6][i & 63] = h[i];
  __syncthreads();
  const int n = blockIdx.x * 256 + t;
  float4 wr[16];
  const float4* w4 = reinterpret_cast<const float4*>(w2 + (size_t)n * 64);
#pragma unroll
  for (int k = 0; k < 16; ++k) wr[k] = w4[k];
  const float bias = b2[n];
  for (int b = 0; b < 32; ++b) {
    const float4* hb = reinterpret_cast<const float4*>(hs[b]);
    float acc = bias;
#pragma unroll
    for (int k = 0; k < 16; ++k) {
      float4 hv = hb[k];
      acc += wr[k].x * hv.x + wr[k].y * hv.y + wr[k].z * hv.z + wr[k].w * hv.w;
    }
    wout[(size_t)b * 65536 + n] = acc;
  }
}

// ---------------- Kernel 4: Sinkhorn (scaling-vector form), K in registers ----------------
// 1 block per batch, 1024 threads, thread owns 8x8 tile of K.
__global__ __launch_bounds__(1024) void sink_k(const float* __restrict__ Wsrc,
                                               unsigned short* __restrict__ Mout) {
  const int b = blockIdx.x;
  const int t = threadIdx.x;
  const int ti = t >> 5, tj = t & 31;
  const int R0 = ti * 8, C0 = tj * 8;
  const float* W = Wsrc + (size_t)b * 65536;

  float A[8][8];
#pragma unroll
  for (int ii = 0; ii < 8; ++ii) {
    float4 v0 = *reinterpret_cast<const float4*>(W + (size_t)(R0 + ii) * 256 + C0);
    float4 v1 = *reinterpret_cast<const float4*>(W + (size_t)(R0 + ii) * 256 + C0 + 4);
    float tmp[8] = {v0.x, v0.y, v0.z, v0.w, v1.x, v1.y, v1.z, v1.w};
#pragma unroll
    for (int jj = 0; jj < 8; ++jj) {
      float v = tmp[jj];
      A[ii][jj] = isfinite(v) ? v : 0.0f;  // nan_to_num
    }
  }
  // row max over all 256 cols (8 local + butterfly over 32 tj-lanes)
  float rmax[8];
#pragma unroll
  for (int ii = 0; ii < 8; ++ii) {
    float m = A[ii][0];
#pragma unroll
    for (int jj = 1; jj < 8; ++jj) m = fmaxf(m, A[ii][jj]);
    rmax[ii] = m;
  }
#pragma unroll
  for (int msk = 1; msk < 32; msk <<= 1)
#pragma unroll
    for (int ii = 0; ii < 8; ++ii) rmax[ii] = fmaxf(rmax[ii], __shfl_xor(rmax[ii], msk));
#pragma unroll
  for (int ii = 0; ii < 8; ++ii)
#pragma unroll
    for (int jj = 0; jj < 8; ++jj) A[ii][jj] = __expf(A[ii][jj] - rmax[ii]);

  float ru[8], cv[8];
#pragma unroll
  for (int k = 0; k < 8; ++k) { ru[k] = 1.0f; cv[k] = 1.0f; }

  __shared__ float part[16][256];   // per-wave column partials
  __shared__ float colsum[256];
  const int w = t >> 6;

  for (int it = 0; it < 20; ++it) {
    // ---- row phase: s_i = ru_i * sum_j A_ij cv_j ; ru_i /= (s_i + eps)
    float p[8];
#pragma unroll
    for (int ii = 0; ii < 8; ++ii) {
      float s = 0.0f;
#pragma unroll
      for (int jj = 0; jj < 8; ++jj) s += A[ii][jj] * cv[jj];
      p[ii] = s;
    }
#pragma unroll
    for (int msk = 1; msk < 32; msk <<= 1)
#pragma unroll
      for (int ii = 0; ii < 8; ++ii) p[ii] += __shfl_xor(p[ii], msk);
#pragma unroll
    for (int ii = 0; ii < 8; ++ii)
      ru[ii] = ru[ii] * __builtin_amdgcn_rcpf(ru[ii] * p[ii] + SK_EPS);

    // ---- col phase: t_j = cv_j * sum_i A_ij ru_i ; cv_j /= (t_j + eps)
    float q[8];
#pragma unroll
    for (int jj = 0; jj < 8; ++jj) {
      float s = 0.0f;
#pragma unroll
      for (int ii = 0; ii < 8; ++ii) s += A[ii][jj] * ru[ii];
      q[jj] = s;
    }
#pragma unroll
    for (int jj = 0; jj < 8; ++jj) q[jj] += __shfl_xor(q[jj], 32);  // merge ti pair in wave
    if ((t & 32) == 0) {
      float4 q0 = {q[0], q[1], q[2], q[3]};
      float4 q1 = {q[4], q[5], q[6], q[7]};
      *reinterpret_cast<float4*>(&part[w][tj * 8]) = q0;
      *reinterpret_cast<float4*>(&part[w][tj * 8 + 4]) = q1;
    }
    __syncthreads();
    if (t < 256) {
      float s = 0.0f;
#pragma unroll
      for (int ww = 0; ww < 16; ++ww) s += part[ww][t];
      colsum[t] = s;
    }
    __syncthreads();
    float4 c0 = *reinterpret_cast<float4*>(&colsum[C0]);
    float4 c1 = *reinterpret_cast<float4*>(&colsum[C0 + 4]);
    float cs[8] = {c0.x, c0.y, c0.z, c0.w, c1.x, c1.y, c1.z, c1.w};
#pragma unroll
    for (int jj = 0; jj < 8; ++jj)
      cv[jj] = cv[jj] * __builtin_amdgcn_rcpf(cv[jj] * cs[jj] + SK_EPS);
  }

  // write M = diag(ru) K diag(cv) as bf16
  unsigned short* Mo = Mout + (size_t)b * 65536;
#pragma unroll
  for (int ii = 0; ii < 8; ++ii) {
    unsigned int pk[4];
#pragma unroll
    for (int hh = 0; hh < 4; ++hh) {
      float f0 = ru[ii] * A[ii][2 * hh] * cv[2 * hh];
      float f1 = ru[ii] * A[ii][2 * hh + 1] * cv[2 * hh + 1];
      pk[hh] = (unsigned int)f2bf(f0) | ((unsigned int)f2bf(f1) << 16);
    }
    uint4 u = {pk[0], pk[1], pk[2], pk[3]};
    *reinterpret_cast<uint4*>(Mo + (size_t)(R0 + ii) * 256 + C0) = u;
  }
}

// ---------------- Kernel 5: out = x + scale * (M @ x), MFMA bf16 ----------------
// grid (128 s-tiles, 32 batches), 512 threads; BM=256 (all rows), BN=32, K=256.
__global__ __launch_bounds__(512) void mix_k(const float* __restrict__ x,
                                             const unsigned short* __restrict__ M,
                                             const float* __restrict__ scale,
                                             float* __restrict__ out) {
  const int sb = blockIdx.x;
  const int b = blockIdx.y;
  const int s0 = sb * 32;
  const float* xb = x + (size_t)b * 1048576;  // 256*4096
  float* ob = out + (size_t)b * 1048576;
  const unsigned short* Mb = M + (size_t)b * 65536;

  __shared__ __align__(16) unsigned short XT[8192];  // [32 s][256 k] bf16, XOR-swizzled
  char* XTb = reinterpret_cast<char*>(XT);
  const int t = threadIdx.x;

  // stage X^T (convert fp32 -> bf16, transpose into LDS)
#pragma unroll
  for (int it = 0; it < 4; ++it) {
    int fidx = t + it * 512;
    int j = fidx >> 3, sq = fidx & 7;
    float4 v = *reinterpret_cast<const float4*>(xb + (size_t)j * 4096 + s0 + sq * 4);
    float vv[4] = {v.x, v.y, v.z, v.w};
#pragma unroll
    for (int c = 0; c < 4; ++c) {
      int sl = sq * 4 + c;
      int byteoff = (sl * 512 + j * 2) ^ ((sl & 7) << 4);
      *reinterpret_cast<unsigned short*>(XTb + byteoff) = f2bf(vv[c]);
    }
  }
  __syncthreads();

  const int lane = t & 63, wave = t >> 6;
  const int wrow = wave >> 1;  // i-base = wrow*64
  const int wcol = wave & 1;   // s-base local = wcol*16
  const int l15 = lane & 15, l4 = lane >> 4;

  f32x4 acc[4] = {{0.f, 0.f, 0.f, 0.f}, {0.f, 0.f, 0.f, 0.f},
                  {0.f, 0.f, 0.f, 0.f}, {0.f, 0.f, 0.f, 0.f}};

  const int sl = wcol * 16 + l15;
#pragma unroll
  for (int k0 = 0; k0 < 256; k0 += 32) {
    int bo = (sl * 512 + (k0 + l4 * 8) * 2) ^ ((sl & 7) << 4);
    short8 bfrag = *reinterpret_cast<const short8*>(XTb + bo);
#pragma unroll
    for (int mf = 0; mf < 4; ++mf) {
      int i = wrow * 64 + mf * 16 + l15;
      short8 afrag = *reinterpret_cast<const short8*>(Mb + (size_t)i * 256 + k0 + l4 * 8);
      acc[mf] = __builtin_amdgcn_mfma_f32_16x16x32_bf16(afrag, bfrag, acc[mf], 0, 0, 0);
    }
  }

  const float sc = scale[0];
#pragma unroll
  for (int mf = 0; mf < 4; ++mf) {
#pragma unroll
    for (int r = 0; r < 4; ++r) {
      int i = wrow * 64 + mf * 16 + l4 * 4 + r;
      int s = s0 + wcol * 16 + l15;
      size_t off = (size_t)i * 4096 + s;
      ob[off] = xb[off] + sc * acc[mf][r];
    }
  }
}

extern "C" void kernel_launch(void* const* d_in, const int* in_sizes, int n_in,
                              void* d_out, int out_size, void* d_ws, size_t ws_size,
                              hipStream_t stream) {
  const float* x = (const float*)d_in[0];
  const float* w1 = (const float*)d_in[1];
  const float* b1 = (const float*)d_in[2];
  const float* w2 = (const float*)d_in[3];
  const float* b2 = (const float*)d_in[4];
  const float* scale = (const float*)d_in[5];
  float* out = (float*)d_out;

  char* ws = (char*)d_ws;
  float* pooled = (float*)(ws);                              // 32 KiB
  float* hbuf = (float*)(ws + 32768);                        // 8 KiB
  float* wbuf = (float*)(ws + 40960);                        // 8 MiB
  unsigned short* Mbuf = (unsigned short*)(ws + 40960 + 8388608);  // 4 MiB

  pool_k<<<8192, 256, 0, stream>>>(x, pooled);
  h_k<<<32, 64, 0, stream>>>(pooled, w1, b1, hbuf);
  wgen_k<<<256, 256, 0, stream>>>(hbuf, w2, b2, wbuf);
  sink_k<<<32, 1024, 0, stream>>>(wbuf, Mbuf);
  mix_k<<<dim3(128, 32), 512, 0, stream>>>(x, Mbuf, scale, out);
}